// Round 1
// baseline (1157.517 us; speedup 1.0000x reference)
//
#include <hip/hip_runtime.h>

// ---------------------------------------------------------------------------
// DUPLEX GAT: 2 channels (am/ph) x 2 GATConv layers on a shared edge list.
// Plan per call:
//   1. Build dst-CSR once (histogram + scan + atomic fill), reused by all 4 convs.
//   2. Per conv: ft = X @ W (fp32 register-tiled GEMM, X^T staged in LDS),
//      el/er per-head dots, then one-pass online-softmax aggregation
//      (flash-style m/l/acc per (node, head, feat) thread; no float atomics).
// ---------------------------------------------------------------------------

__global__ void hist_kernel(const int* __restrict__ dst, int* __restrict__ counts, int E) {
  int e = blockIdx.x * blockDim.x + threadIdx.x;
  if (e < E) atomicAdd(&counts[dst[e]], 1);
}

__global__ __launch_bounds__(1024) void scan_kernel(const int* __restrict__ counts,
                                                    int* __restrict__ offsets, int n) {
  __shared__ int lds[1024];
  int tid = threadIdx.x;
  int carry = 0;
  for (int base = 0; base < n; base += 1024) {
    int i = base + tid;
    int v = (i < n) ? counts[i] : 0;
    lds[tid] = v;
    __syncthreads();
    for (int off = 1; off < 1024; off <<= 1) {
      int t = (tid >= off) ? lds[tid - off] : 0;
      __syncthreads();
      lds[tid] += t;
      __syncthreads();
    }
    int incl = lds[tid];
    if (i < n) offsets[i] = carry + incl - v;  // exclusive
    int total = lds[1023];
    __syncthreads();  // protect lds before next chunk overwrites
    carry += total;
  }
  if (tid == 0) offsets[n] = carry;
}

__global__ void fill_kernel(const int* __restrict__ src, const int* __restrict__ dst,
                            const float* __restrict__ exist, const float* __restrict__ am_exist,
                            const int* __restrict__ offsets, int* __restrict__ cursor,
                            int* __restrict__ csr_src, float* __restrict__ w_am,
                            float* __restrict__ w_ph, int E) {
  int e = blockIdx.x * blockDim.x + threadIdx.x;
  if (e >= E) return;
  int d = dst[e];
  int pos = offsets[d] + atomicAdd(&cursor[d], 1);
  csr_src[pos] = src[e];
  w_am[pos] = am_exist[e];  // am channel weight
  w_ph[pos] = exist[e];     // ph channel weight
}

// Y[n x 128] = X[n x 128] @ W[128 x 128], fp32.
// 128x128 block tile, 8x8 register tile/thread, X^T staged in LDS (64 KB).
__global__ __launch_bounds__(256) void gemm_kernel(const float* __restrict__ X,
                                                   const float* __restrict__ W,
                                                   float* __restrict__ Y, int n) {
  __shared__ float xs[128][128];  // xs[k][r] — transposed so compute reads are b128
  int row0 = blockIdx.x << 7;
  int t = threadIdx.x;
  // Stage: lanes sweep r (conflict-free LDS writes, banks = r%32, 2-way free);
  // global reads per-row float4 strips, fully consumed across iterations (L1).
  for (int i = 0; i < 16; ++i) {
    int idx = t + (i << 8);
    int r = idx & 127;
    int k4 = idx >> 7;  // 0..31
    int row = row0 + r;
    float4 v = make_float4(0.f, 0.f, 0.f, 0.f);
    if (row < n) v = *(const float4*)(X + (size_t)row * 128 + (k4 << 2));
    xs[(k4 << 2) + 0][r] = v.x;
    xs[(k4 << 2) + 1][r] = v.y;
    xs[(k4 << 2) + 2][r] = v.z;
    xs[(k4 << 2) + 3][r] = v.w;
  }
  __syncthreads();
  int tx = t & 15;  // cols tx*8..+7
  int ty = t >> 4;  // rows ty*8..+7
  const float4* W4 = (const float4*)W;
  float acc[8][8];
#pragma unroll
  for (int r = 0; r < 8; ++r)
#pragma unroll
    for (int c = 0; c < 8; ++c) acc[r][c] = 0.f;
#pragma unroll 4
  for (int k = 0; k < 128; ++k) {
    float4 w0 = W4[(k << 5) + (tx << 1)];
    float4 w1 = W4[(k << 5) + (tx << 1) + 1];
    float4 x0 = *(const float4*)&xs[k][(ty << 3)];
    float4 x1 = *(const float4*)&xs[k][(ty << 3) + 4];
    float xv[8] = {x0.x, x0.y, x0.z, x0.w, x1.x, x1.y, x1.z, x1.w};
    float wv[8] = {w0.x, w0.y, w0.z, w0.w, w1.x, w1.y, w1.z, w1.w};
#pragma unroll
    for (int r = 0; r < 8; ++r)
#pragma unroll
      for (int c = 0; c < 8; ++c) acc[r][c] = fmaf(xv[r], wv[c], acc[r][c]);
  }
#pragma unroll
  for (int r = 0; r < 8; ++r) {
    int row = row0 + (ty << 3) + r;
    if (row < n) {
      float4* yp = (float4*)(Y + (size_t)row * 128 + (tx << 3));
      yp[0] = make_float4(acc[r][0], acc[r][1], acc[r][2], acc[r][3]);
      yp[1] = make_float4(acc[r][4], acc[r][5], acc[r][6], acc[r][7]);
    }
  }
}

// el[i][h] = sum_f ft[i][h*32+f]*al[h*32+f];  er likewise. One block (128 thr) per node.
__global__ __launch_bounds__(128) void elr_kernel(const float* __restrict__ ft,
                                                  const float* __restrict__ al,
                                                  const float* __restrict__ ar,
                                                  float* __restrict__ el,
                                                  float* __restrict__ er, int n) {
  int i = blockIdx.x;
  int j = threadIdx.x;
  float f = ft[(size_t)i * 128 + j];
  float pl = f * al[j];
  float pr = f * ar[j];
#pragma unroll
  for (int off = 16; off > 0; off >>= 1) {  // xor <=16 stays within 32-lane head group
    pl += __shfl_xor(pl, off);
    pr += __shfl_xor(pr, off);
  }
  if ((j & 31) == 0) {
    int h = j >> 5;
    el[i * 4 + h] = pl;
    er[i * 4 + h] = pr;
  }
}

// Online-softmax aggregation. One thread per (node, head, feat): j = h*32+f.
// LAYER 0: out[node][128] = relu(acc/l + bias).  LAYER 1: out[node][32] = mean_h(acc/l + bias).
template <int LAYER>
__global__ __launch_bounds__(256) void agg_kernel(
    const float* __restrict__ ft, const float* __restrict__ el, const float* __restrict__ er,
    const int* __restrict__ offsets, const int* __restrict__ csr_src,
    const float* __restrict__ csr_w, const float* __restrict__ bias,
    float* __restrict__ out, int n) {
  int local = threadIdx.x >> 7;  // 2 nodes per block
  int node = (blockIdx.x << 1) + local;
  int j = threadIdx.x & 127;
  int h = j >> 5;
  __shared__ float red[256];
  float m = -INFINITY, l = 0.f, acc = 0.f;
  if (node < n) {
    int start = offsets[node];
    int end = offsets[node + 1];
    float er_i = er[node * 4 + h];
    for (int k = start; k < end; ++k) {
      int s = csr_src[k];
      float w = csr_w[k];
      float e = el[s * 4 + h] + er_i;
      e = (e > 0.f) ? e : 0.2f * e;  // leaky relu 0.2
      float mn = fmaxf(m, e);
      float scale = __expf(m - mn);  // exp(-inf)=0 on first edge
      float p = __expf(e - mn);
      l = l * scale + p;
      acc = acc * scale + p * w * ft[(size_t)s * 128 + j];
      m = mn;
    }
  }
  float v = acc / fmaxf(l, 1e-9f);  // isolated node -> 0, matches ref guard
  if (LAYER == 0) {
    if (node < n) out[(size_t)node * 128 + j] = fmaxf(v + bias[j], 0.f);
  } else {
    red[threadIdx.x] = v + bias[j];
    __syncthreads();
    if (j < 32 && node < n) {
      int base = local << 7;
      float s4 = red[base + j] + red[base + j + 32] + red[base + j + 64] + red[base + j + 96];
      out[(size_t)node * 32 + j] = 0.25f * s4;
    }
  }
}

extern "C" void kernel_launch(void* const* d_in, const int* in_sizes, int n_in,
                              void* d_out, int out_size, void* d_ws, size_t ws_size,
                              hipStream_t stream) {
  const float* x_am = (const float*)d_in[0];
  const float* x_ph = (const float*)d_in[1];
  const float* exist = (const float*)d_in[2];
  const float* am_exist = (const float*)d_in[3];
  const int* src = (const int*)d_in[4];
  const int* dst = (const int*)d_in[5];
  const float* W0a = (const float*)d_in[6];
  const float* al0a = (const float*)d_in[7];
  const float* ar0a = (const float*)d_in[8];
  const float* b0a = (const float*)d_in[9];
  const float* W0p = (const float*)d_in[10];
  const float* al0p = (const float*)d_in[11];
  const float* ar0p = (const float*)d_in[12];
  const float* b0p = (const float*)d_in[13];
  const float* W1a = (const float*)d_in[14];
  const float* al1a = (const float*)d_in[15];
  const float* ar1a = (const float*)d_in[16];
  const float* b1a = (const float*)d_in[17];
  const float* W1p = (const float*)d_in[18];
  const float* al1p = (const float*)d_in[19];
  const float* ar1p = (const float*)d_in[20];
  const float* b1p = (const float*)d_in[21];

  int n = in_sizes[0] / 128;  // 50000
  int E = in_sizes[2];        // 800000
  int N_pad = (n + 3) & ~3;

  // Workspace layout (all 16B-aligned by construction): ~63 MB total.
  char* p = (char*)d_ws;
  int* counts = (int*)p;   p += (size_t)N_pad * 4;
  int* offsets = (int*)p;  p += (size_t)(N_pad + 4) * 4;
  int* cursor = (int*)p;   p += (size_t)N_pad * 4;
  int* csr_src = (int*)p;  p += (size_t)E * 4;
  float* w_am = (float*)p; p += (size_t)E * 4;
  float* w_ph = (float*)p; p += (size_t)E * 4;
  float* ft = (float*)p;   p += (size_t)n * 128 * 4;
  float* hbuf = (float*)p; p += (size_t)n * 128 * 4;
  float* el = (float*)p;   p += (size_t)N_pad * 4 * 4;
  float* er = (float*)p;   p += (size_t)N_pad * 4 * 4;

  // ---- CSR build (shared by all 4 convs) ----
  hipMemsetAsync(counts, 0, (size_t)n * 4, stream);
  hist_kernel<<<(E + 255) / 256, 256, 0, stream>>>(dst, counts, E);
  scan_kernel<<<1, 1024, 0, stream>>>(counts, offsets, n);
  hipMemsetAsync(cursor, 0, (size_t)n * 4, stream);
  fill_kernel<<<(E + 255) / 256, 256, 0, stream>>>(src, dst, exist, am_exist, offsets,
                                                   cursor, csr_src, w_am, w_ph, E);

  int gemm_grid = (n + 127) / 128;
  int agg_grid = (n + 1) / 2;
  float* out_am = (float*)d_out;
  float* out_ph = out_am + (size_t)n * 32;

  // ---- AM channel (edge weight = am_exist) ----
  gemm_kernel<<<gemm_grid, 256, 0, stream>>>(x_am, W0a, ft, n);
  elr_kernel<<<n, 128, 0, stream>>>(ft, al0a, ar0a, el, er, n);
  agg_kernel<0><<<agg_grid, 256, 0, stream>>>(ft, el, er, offsets, csr_src, w_am, b0a, hbuf, n);
  gemm_kernel<<<gemm_grid, 256, 0, stream>>>(hbuf, W1a, ft, n);
  elr_kernel<<<n, 128, 0, stream>>>(ft, al1a, ar1a, el, er, n);
  agg_kernel<1><<<agg_grid, 256, 0, stream>>>(ft, el, er, offsets, csr_src, w_am, b1a, out_am, n);

  // ---- PH channel (edge weight = exist) ----
  gemm_kernel<<<gemm_grid, 256, 0, stream>>>(x_ph, W0p, ft, n);
  elr_kernel<<<n, 128, 0, stream>>>(ft, al0p, ar0p, el, er, n);
  agg_kernel<0><<<agg_grid, 256, 0, stream>>>(ft, el, er, offsets, csr_src, w_ph, b0p, hbuf, n);
  gemm_kernel<<<gemm_grid, 256, 0, stream>>>(hbuf, W1p, ft, n);
  elr_kernel<<<n, 128, 0, stream>>>(ft, al1p, ar1p, el, er, n);
  agg_kernel<1><<<agg_grid, 256, 0, stream>>>(ft, el, er, offsets, csr_src, w_ph, b1p, out_ph, n);
}

// Round 2
// 700.002 us; speedup vs baseline: 1.6536x; 1.6536x over previous
//
#include <hip/hip_runtime.h>

// ---------------------------------------------------------------------------
// DUPLEX GAT, round 2.
//   - CSR build: hist + 3-kernel parallel scan + atomic fill (shared by 4 convs)
//   - Per conv: GEMM (fp32 reg-tiled, fused el/er epilogue) ->
//               stats (per-node softmax m, 1/l; edge-parallel, 16 lanes/node) ->
//               gather (pure FMA accumulate, LDS-staged indices, unroll-4)
// ---------------------------------------------------------------------------

__global__ void hist_kernel(const int* __restrict__ dst, int* __restrict__ counts, int E) {
  int e = blockIdx.x * blockDim.x + threadIdx.x;
  if (e < E) atomicAdd(&counts[dst[e]], 1);
}

// Per-256-block inclusive scan + block sums.
__global__ __launch_bounds__(256) void scan1_kernel(const int* __restrict__ counts,
                                                    int* __restrict__ incl,
                                                    int* __restrict__ bsum, int n) {
  __shared__ int lds[256];
  int i = blockIdx.x * 256 + threadIdx.x;
  int v = (i < n) ? counts[i] : 0;
  lds[threadIdx.x] = v;
  __syncthreads();
  for (int off = 1; off < 256; off <<= 1) {
    int t = (threadIdx.x >= off) ? lds[threadIdx.x - off] : 0;
    __syncthreads();
    lds[threadIdx.x] += t;
    __syncthreads();
  }
  if (i < n) incl[i] = lds[threadIdx.x];
  if (threadIdx.x == 255) bsum[blockIdx.x] = lds[255];
}

// Single-block exclusive scan of block sums (nb ~ 196).
__global__ __launch_bounds__(256) void scan2_kernel(int* __restrict__ bsum, int nb) {
  __shared__ int lds[256];
  int carry = 0;
  for (int base = 0; base < nb; base += 256) {
    int i = base + threadIdx.x;
    int v = (i < nb) ? bsum[i] : 0;
    lds[threadIdx.x] = v;
    __syncthreads();
    for (int off = 1; off < 256; off <<= 1) {
      int t = (threadIdx.x >= off) ? lds[threadIdx.x - off] : 0;
      __syncthreads();
      lds[threadIdx.x] += t;
      __syncthreads();
    }
    if (i < nb) bsum[i] = carry + lds[threadIdx.x] - v;  // exclusive
    carry += lds[255];
    __syncthreads();
  }
}

__global__ void scan3_kernel(const int* __restrict__ counts, const int* __restrict__ incl,
                             const int* __restrict__ bsum_ex, int* __restrict__ offsets,
                             int n, int E) {
  int i = blockIdx.x * blockDim.x + threadIdx.x;
  if (i < n) offsets[i] = incl[i] - counts[i] + bsum_ex[i >> 8];
  if (i == 0) offsets[n] = E;
}

__global__ void fill_kernel(const int* __restrict__ src, const int* __restrict__ dst,
                            const float* __restrict__ exist, const float* __restrict__ am_exist,
                            const int* __restrict__ offsets, int* __restrict__ cursor,
                            int* __restrict__ csr_src, float* __restrict__ w_am,
                            float* __restrict__ w_ph, int E) {
  int e = blockIdx.x * blockDim.x + threadIdx.x;
  if (e >= E) return;
  int d = dst[e];
  int pos = offsets[d] + atomicAdd(&cursor[d], 1);
  csr_src[pos] = src[e];
  w_am[pos] = am_exist[e];
  w_ph[pos] = exist[e];
}

// Y[n x 128] = X[n x 128] @ W[128 x 128], fp32; fused el/er epilogue.
__global__ __launch_bounds__(256) void gemm_kernel(const float* __restrict__ X,
                                                   const float* __restrict__ W,
                                                   const float* __restrict__ al,
                                                   const float* __restrict__ ar,
                                                   float* __restrict__ Y,
                                                   float* __restrict__ el,
                                                   float* __restrict__ er, int n) {
  __shared__ float xs[128][128];  // xs[k][r]
  int row0 = blockIdx.x << 7;
  int t = threadIdx.x;
  for (int i = 0; i < 16; ++i) {
    int idx = t + (i << 8);
    int r = idx & 127;
    int k4 = idx >> 7;
    int row = row0 + r;
    float4 v = make_float4(0.f, 0.f, 0.f, 0.f);
    if (row < n) v = *(const float4*)(X + (size_t)row * 128 + (k4 << 2));
    xs[(k4 << 2) + 0][r] = v.x;
    xs[(k4 << 2) + 1][r] = v.y;
    xs[(k4 << 2) + 2][r] = v.z;
    xs[(k4 << 2) + 3][r] = v.w;
  }
  __syncthreads();
  int tx = t & 15;  // cols tx*8..+7 (within one head: head = tx>>2)
  int ty = t >> 4;  // rows ty*8..+7
  const float4* W4 = (const float4*)W;
  float acc[8][8];
#pragma unroll
  for (int r = 0; r < 8; ++r)
#pragma unroll
    for (int c = 0; c < 8; ++c) acc[r][c] = 0.f;
#pragma unroll 4
  for (int k = 0; k < 128; ++k) {
    float4 w0 = W4[(k << 5) + (tx << 1)];
    float4 w1 = W4[(k << 5) + (tx << 1) + 1];
    float4 x0 = *(const float4*)&xs[k][(ty << 3)];
    float4 x1 = *(const float4*)&xs[k][(ty << 3) + 4];
    float xv[8] = {x0.x, x0.y, x0.z, x0.w, x1.x, x1.y, x1.z, x1.w};
    float wv[8] = {w0.x, w0.y, w0.z, w0.w, w1.x, w1.y, w1.z, w1.w};
#pragma unroll
    for (int r = 0; r < 8; ++r)
#pragma unroll
      for (int c = 0; c < 8; ++c) acc[r][c] = fmaf(xv[r], wv[c], acc[r][c]);
  }
#pragma unroll
  for (int r = 0; r < 8; ++r) {
    int row = row0 + (ty << 3) + r;
    if (row < n) {
      float4* yp = (float4*)(Y + (size_t)row * 128 + (tx << 3));
      yp[0] = make_float4(acc[r][0], acc[r][1], acc[r][2], acc[r][3]);
      yp[1] = make_float4(acc[r][4], acc[r][5], acc[r][6], acc[r][7]);
    }
  }
  // ---- fused el/er epilogue (cols of one thread lie within a single head) ----
  float al_v[8], ar_v[8];
  {
    const float4* al4 = (const float4*)al;
    const float4* ar4 = (const float4*)ar;
    float4 a0 = al4[tx * 2], a1 = al4[tx * 2 + 1];
    float4 r0 = ar4[tx * 2], r1 = ar4[tx * 2 + 1];
    al_v[0] = a0.x; al_v[1] = a0.y; al_v[2] = a0.z; al_v[3] = a0.w;
    al_v[4] = a1.x; al_v[5] = a1.y; al_v[6] = a1.z; al_v[7] = a1.w;
    ar_v[0] = r0.x; ar_v[1] = r0.y; ar_v[2] = r0.z; ar_v[3] = r0.w;
    ar_v[4] = r1.x; ar_v[5] = r1.y; ar_v[6] = r1.z; ar_v[7] = r1.w;
  }
  __syncthreads();  // xs reuse as reduction scratch
  float* redl = &xs[0][0];          // [128][17] padded
  float* redr = redl + 128 * 17;    // [128][17]
#pragma unroll
  for (int r = 0; r < 8; ++r) {
    float pl = 0.f, pr = 0.f;
#pragma unroll
    for (int c = 0; c < 8; ++c) {
      pl = fmaf(acc[r][c], al_v[c], pl);
      pr = fmaf(acc[r][c], ar_v[c], pr);
    }
    redl[((ty << 3) + r) * 17 + tx] = pl;
    redr[((ty << 3) + r) * 17 + tx] = pr;
  }
  __syncthreads();
  if (t < 128) {
    int row = row0 + t;
    if (row < n) {
      float s[4], q[4];
#pragma unroll
      for (int h = 0; h < 4; ++h) {
        int b = t * 17 + h * 4;
        s[h] = redl[b] + redl[b + 1] + redl[b + 2] + redl[b + 3];
        q[h] = redr[b] + redr[b + 1] + redr[b + 2] + redr[b + 3];
      }
      *(float4*)(el + (size_t)row * 4) = make_float4(s[0], s[1], s[2], s[3]);
      *(float4*)(er + (size_t)row * 4) = make_float4(q[0], q[1], q[2], q[3]);
    }
  }
}

// Per-(node,head) softmax stats: m = max_e, rl = 1/max(sum exp(e-m), 1e-9).
// 16 lanes per node, edge-parallel, butterfly (m,l) combine.
__global__ __launch_bounds__(256) void stats_kernel(
    const float* __restrict__ el, const float* __restrict__ er,
    const int* __restrict__ offsets, const int* __restrict__ csr_src,
    float* __restrict__ stat_m, float* __restrict__ stat_rl, int n) {
  int lane16 = threadIdx.x & 15;
  int node = blockIdx.x * 16 + (threadIdx.x >> 4);
  if (node >= n) return;  // whole 16-lane groups exit together; shfl stays in-group
  int start = offsets[node], end = offsets[node + 1];
  float4 er4 = *(const float4*)(er + (size_t)node * 4);
  float erv[4] = {er4.x, er4.y, er4.z, er4.w};
  float m[4] = {-INFINITY, -INFINITY, -INFINITY, -INFINITY};
  float l[4] = {0.f, 0.f, 0.f, 0.f};
  for (int k = start + lane16; k < end; k += 16) {
    int s = csr_src[k];
    float4 e4 = *(const float4*)(el + (size_t)s * 4);
    float ev[4] = {e4.x, e4.y, e4.z, e4.w};
#pragma unroll
    for (int h = 0; h < 4; ++h) {
      float e = ev[h] + erv[h];
      e = (e > 0.f) ? e : 0.2f * e;
      float mn = fmaxf(m[h], e);
      // fmaxf(-,-80) turns (-inf)-(-inf)=NaN into -80 -> exp ~ 0 (NaN-safe)
      l[h] = l[h] * __expf(fmaxf(m[h] - mn, -80.f)) + __expf(fmaxf(e - mn, -80.f));
      m[h] = mn;
    }
  }
#pragma unroll
  for (int off = 1; off < 16; off <<= 1) {
#pragma unroll
    for (int h = 0; h < 4; ++h) {
      float mo = __shfl_xor(m[h], off);
      float lo = __shfl_xor(l[h], off);
      float mn = fmaxf(m[h], mo);
      l[h] = l[h] * __expf(fmaxf(m[h] - mn, -80.f)) + lo * __expf(fmaxf(mo - mn, -80.f));
      m[h] = mn;
    }
  }
  if (lane16 == 0) {
    *(float4*)(stat_m + (size_t)node * 4) = make_float4(m[0], m[1], m[2], m[3]);
    *(float4*)(stat_rl + (size_t)node * 4) =
        make_float4(1.f / fmaxf(l[0], 1e-9f), 1.f / fmaxf(l[1], 1e-9f),
                    1.f / fmaxf(l[2], 1e-9f), 1.f / fmaxf(l[3], 1e-9f));
  }
}

// Weighted gather-accumulate. One node per 128-thread block; j = h*32+f.
// LAYER 0: out[node][128] = relu(acc + bias). LAYER 1: out[node][32] = mean_h(acc + bias).
template <int LAYER>
__global__ __launch_bounds__(128) void gather_kernel(
    const float* __restrict__ ft, const float* __restrict__ el,
    const float* __restrict__ er, const float* __restrict__ stat_m,
    const float* __restrict__ stat_rl, const int* __restrict__ offsets,
    const int* __restrict__ csr_src, const float* __restrict__ csr_w,
    const float* __restrict__ bias, float* __restrict__ out, int n) {
  int node = blockIdx.x;
  int j = threadIdx.x;
  int h = j >> 5;
  int start = offsets[node], end = offsets[node + 1];
  float er_h = er[(size_t)node * 4 + h];
  float m_h = stat_m[(size_t)node * 4 + h];
  float rl_h = stat_rl[(size_t)node * 4 + h];
  __shared__ int s_src[64];
  __shared__ float s_w[64];
  float acc = 0.f;
  for (int base = start; base < end; base += 64) {
    int cnt = min(64, end - base);
    __syncthreads();
    if (j < cnt) {
      s_src[j] = csr_src[base + j];
      s_w[j] = csr_w[base + j];
    }
    __syncthreads();
    int k = 0;
    for (; k + 4 <= cnt; k += 4) {
      int s0 = s_src[k], s1 = s_src[k + 1], s2 = s_src[k + 2], s3 = s_src[k + 3];
      float w0 = s_w[k], w1 = s_w[k + 1], w2 = s_w[k + 2], w3 = s_w[k + 3];
      float el0 = el[(size_t)s0 * 4 + h], el1 = el[(size_t)s1 * 4 + h];
      float el2 = el[(size_t)s2 * 4 + h], el3 = el[(size_t)s3 * 4 + h];
      float f0 = ft[(size_t)s0 * 128 + j], f1 = ft[(size_t)s1 * 128 + j];
      float f2 = ft[(size_t)s2 * 128 + j], f3 = ft[(size_t)s3 * 128 + j];
      float e0 = el0 + er_h; e0 = (e0 > 0.f) ? e0 : 0.2f * e0;
      float e1 = el1 + er_h; e1 = (e1 > 0.f) ? e1 : 0.2f * e1;
      float e2 = el2 + er_h; e2 = (e2 > 0.f) ? e2 : 0.2f * e2;
      float e3 = el3 + er_h; e3 = (e3 > 0.f) ? e3 : 0.2f * e3;
      acc = fmaf(__expf(e0 - m_h) * rl_h * w0, f0, acc);
      acc = fmaf(__expf(e1 - m_h) * rl_h * w1, f1, acc);
      acc = fmaf(__expf(e2 - m_h) * rl_h * w2, f2, acc);
      acc = fmaf(__expf(e3 - m_h) * rl_h * w3, f3, acc);
    }
    for (; k < cnt; ++k) {
      int s0 = s_src[k];
      float w0 = s_w[k];
      float el0 = el[(size_t)s0 * 4 + h];
      float f0 = ft[(size_t)s0 * 128 + j];
      float e0 = el0 + er_h; e0 = (e0 > 0.f) ? e0 : 0.2f * e0;
      acc = fmaf(__expf(e0 - m_h) * rl_h * w0, f0, acc);
    }
  }
  if (LAYER == 0) {
    out[(size_t)node * 128 + j] = fmaxf(acc + bias[j], 0.f);
  } else {
    __shared__ float red[128];
    red[j] = acc + bias[j];
    __syncthreads();
    if (j < 32) {
      float s4 = red[j] + red[j + 32] + red[j + 64] + red[j + 96];
      out[(size_t)node * 32 + j] = 0.25f * s4;
    }
  }
}

extern "C" void kernel_launch(void* const* d_in, const int* in_sizes, int n_in,
                              void* d_out, int out_size, void* d_ws, size_t ws_size,
                              hipStream_t stream) {
  const float* x_am = (const float*)d_in[0];
  const float* x_ph = (const float*)d_in[1];
  const float* exist = (const float*)d_in[2];
  const float* am_exist = (const float*)d_in[3];
  const int* src = (const int*)d_in[4];
  const int* dst = (const int*)d_in[5];
  const float* W0a = (const float*)d_in[6];
  const float* al0a = (const float*)d_in[7];
  const float* ar0a = (const float*)d_in[8];
  const float* b0a = (const float*)d_in[9];
  const float* W0p = (const float*)d_in[10];
  const float* al0p = (const float*)d_in[11];
  const float* ar0p = (const float*)d_in[12];
  const float* b0p = (const float*)d_in[13];
  const float* W1a = (const float*)d_in[14];
  const float* al1a = (const float*)d_in[15];
  const float* ar1a = (const float*)d_in[16];
  const float* b1a = (const float*)d_in[17];
  const float* W1p = (const float*)d_in[18];
  const float* al1p = (const float*)d_in[19];
  const float* ar1p = (const float*)d_in[20];
  const float* b1p = (const float*)d_in[21];

  int n = in_sizes[0] / 128;  // 50000
  int E = in_sizes[2];        // 800000
  int N_pad = (n + 3) & ~3;
  int nb = (n + 255) / 256;

  char* p = (char*)d_ws;
  int* counts = (int*)p;    p += (size_t)N_pad * 4;
  int* incl = (int*)p;      p += (size_t)N_pad * 4;
  int* offsets = (int*)p;   p += (size_t)(N_pad + 4) * 4;
  int* cursor = (int*)p;    p += (size_t)N_pad * 4;
  int* bsum = (int*)p;      p += (size_t)((nb + 255) & ~255) * 4;
  int* csr_src = (int*)p;   p += (size_t)E * 4;
  float* w_am = (float*)p;  p += (size_t)E * 4;
  float* w_ph = (float*)p;  p += (size_t)E * 4;
  float* ft = (float*)p;    p += (size_t)n * 128 * 4;
  float* hbuf = (float*)p;  p += (size_t)n * 128 * 4;
  float* el = (float*)p;    p += (size_t)N_pad * 4 * 4;
  float* er = (float*)p;    p += (size_t)N_pad * 4 * 4;
  float* stat_m = (float*)p;  p += (size_t)N_pad * 4 * 4;
  float* stat_rl = (float*)p; p += (size_t)N_pad * 4 * 4;

  // ---- CSR build ----
  hipMemsetAsync(counts, 0, (size_t)n * 4, stream);
  hist_kernel<<<(E + 255) / 256, 256, 0, stream>>>(dst, counts, E);
  scan1_kernel<<<nb, 256, 0, stream>>>(counts, incl, bsum, n);
  scan2_kernel<<<1, 256, 0, stream>>>(bsum, nb);
  scan3_kernel<<<nb, 256, 0, stream>>>(counts, incl, bsum, offsets, n, E);
  hipMemsetAsync(cursor, 0, (size_t)n * 4, stream);
  fill_kernel<<<(E + 255) / 256, 256, 0, stream>>>(src, dst, exist, am_exist, offsets,
                                                   cursor, csr_src, w_am, w_ph, E);

  int gemm_grid = (n + 127) / 128;
  int stats_grid = (n + 15) / 16;
  float* out_am = (float*)d_out;
  float* out_ph = out_am + (size_t)n * 32;

  // ---- AM channel ----
  gemm_kernel<<<gemm_grid, 256, 0, stream>>>(x_am, W0a, al0a, ar0a, ft, el, er, n);
  stats_kernel<<<stats_grid, 256, 0, stream>>>(el, er, offsets, csr_src, stat_m, stat_rl, n);
  gather_kernel<0><<<n, 128, 0, stream>>>(ft, el, er, stat_m, stat_rl, offsets, csr_src,
                                          w_am, b0a, hbuf, n);
  gemm_kernel<<<gemm_grid, 256, 0, stream>>>(hbuf, W1a, al1a, ar1a, ft, el, er, n);
  stats_kernel<<<stats_grid, 256, 0, stream>>>(el, er, offsets, csr_src, stat_m, stat_rl, n);
  gather_kernel<1><<<n, 128, 0, stream>>>(ft, el, er, stat_m, stat_rl, offsets, csr_src,
                                          w_am, b1a, out_am, n);

  // ---- PH channel ----
  gemm_kernel<<<gemm_grid, 256, 0, stream>>>(x_ph, W0p, al0p, ar0p, ft, el, er, n);
  stats_kernel<<<stats_grid, 256, 0, stream>>>(el, er, offsets, csr_src, stat_m, stat_rl, n);
  gather_kernel<0><<<n, 128, 0, stream>>>(ft, el, er, stat_m, stat_rl, offsets, csr_src,
                                          w_ph, b0p, hbuf, n);
  gemm_kernel<<<gemm_grid, 256, 0, stream>>>(hbuf, W1p, al1p, ar1p, ft, el, er, n);
  stats_kernel<<<stats_grid, 256, 0, stream>>>(el, er, offsets, csr_src, stat_m, stat_rl, n);
  gather_kernel<1><<<n, 128, 0, stream>>>(ft, el, er, stat_m, stat_rl, offsets, csr_src,
                                          w_ph, b1p, out_ph, n);
}

// Round 3
// 633.256 us; speedup vs baseline: 1.8279x; 1.1054x over previous
//
#include <hip/hip_runtime.h>

// ---------------------------------------------------------------------------
// DUPLEX GAT, round 3.
//   - dst-CSR build once (hist + parallel scan + atomic fill).
//   - Per layer (both channels batched in each dispatch):
//       GEMM (fp32 reg-tiled, fused el/er epilogue, grid.y = channel)
//       gather (one node per 256-thr block: am=thr 0-127, ph=thr 128-255;
//               LDS-staged per-edge softmax coefs, in-kernel denominator,
//               no separate stats pass, unroll-8 FMA inner loop)
// ---------------------------------------------------------------------------

struct GemmP { const float *X, *W, *al, *ar; float *Y, *el, *er; };
struct ChP   { const float *ft, *el, *er, *w, *bias; float *out; };

__global__ void hist_kernel(const int* __restrict__ dst, int* __restrict__ counts, int E) {
  int e = blockIdx.x * blockDim.x + threadIdx.x;
  if (e < E) atomicAdd(&counts[dst[e]], 1);
}

__global__ __launch_bounds__(256) void scan1_kernel(const int* __restrict__ counts,
                                                    int* __restrict__ incl,
                                                    int* __restrict__ bsum, int n) {
  __shared__ int lds[256];
  int i = blockIdx.x * 256 + threadIdx.x;
  int v = (i < n) ? counts[i] : 0;
  lds[threadIdx.x] = v;
  __syncthreads();
  for (int off = 1; off < 256; off <<= 1) {
    int t = (threadIdx.x >= off) ? lds[threadIdx.x - off] : 0;
    __syncthreads();
    lds[threadIdx.x] += t;
    __syncthreads();
  }
  if (i < n) incl[i] = lds[threadIdx.x];
  if (threadIdx.x == 255) bsum[blockIdx.x] = lds[255];
}

__global__ __launch_bounds__(256) void scan2_kernel(int* __restrict__ bsum, int nb) {
  __shared__ int lds[256];
  int carry = 0;
  for (int base = 0; base < nb; base += 256) {
    int i = base + threadIdx.x;
    int v = (i < nb) ? bsum[i] : 0;
    lds[threadIdx.x] = v;
    __syncthreads();
    for (int off = 1; off < 256; off <<= 1) {
      int t = (threadIdx.x >= off) ? lds[threadIdx.x - off] : 0;
      __syncthreads();
      lds[threadIdx.x] += t;
      __syncthreads();
    }
    if (i < nb) bsum[i] = carry + lds[threadIdx.x] - v;  // exclusive
    carry += lds[255];
    __syncthreads();
  }
}

__global__ void scan3_kernel(const int* __restrict__ counts, const int* __restrict__ incl,
                             const int* __restrict__ bsum_ex, int* __restrict__ offsets,
                             int n, int E) {
  int i = blockIdx.x * blockDim.x + threadIdx.x;
  if (i < n) offsets[i] = incl[i] - counts[i] + bsum_ex[i >> 8];
  if (i == 0) offsets[n] = E;
}

__global__ void fill_kernel(const int* __restrict__ src, const int* __restrict__ dst,
                            const float* __restrict__ exist, const float* __restrict__ am_exist,
                            const int* __restrict__ offsets, int* __restrict__ cursor,
                            int* __restrict__ csr_src, float* __restrict__ w_am,
                            float* __restrict__ w_ph, int E) {
  int e = blockIdx.x * blockDim.x + threadIdx.x;
  if (e >= E) return;
  int d = dst[e];
  int pos = offsets[d] + atomicAdd(&cursor[d], 1);
  csr_src[pos] = src[e];
  w_am[pos] = am_exist[e];
  w_ph[pos] = exist[e];
}

// Y = X @ W (n x 128 @ 128 x 128, fp32) with fused el/er epilogue.
// grid.y selects the channel parameter set.
__global__ __launch_bounds__(256) void gemm_kernel(GemmP p0, GemmP p1, int n) {
  GemmP p = blockIdx.y ? p1 : p0;
  __shared__ float xs[128][128];  // xs[k][r]
  int row0 = blockIdx.x << 7;
  int t = threadIdx.x;
  for (int i = 0; i < 16; ++i) {
    int idx = t + (i << 8);
    int r = idx & 127;
    int k4 = idx >> 7;
    int row = row0 + r;
    float4 v = make_float4(0.f, 0.f, 0.f, 0.f);
    if (row < n) v = *(const float4*)(p.X + (size_t)row * 128 + (k4 << 2));
    xs[(k4 << 2) + 0][r] = v.x;
    xs[(k4 << 2) + 1][r] = v.y;
    xs[(k4 << 2) + 2][r] = v.z;
    xs[(k4 << 2) + 3][r] = v.w;
  }
  __syncthreads();
  int tx = t & 15;  // cols tx*8..+7 (one head per thread-col-group)
  int ty = t >> 4;  // rows ty*8..+7
  const float4* W4 = (const float4*)p.W;
  float acc[8][8];
#pragma unroll
  for (int r = 0; r < 8; ++r)
#pragma unroll
    for (int c = 0; c < 8; ++c) acc[r][c] = 0.f;
#pragma unroll 4
  for (int k = 0; k < 128; ++k) {
    float4 w0 = W4[(k << 5) + (tx << 1)];
    float4 w1 = W4[(k << 5) + (tx << 1) + 1];
    float4 x0 = *(const float4*)&xs[k][(ty << 3)];
    float4 x1 = *(const float4*)&xs[k][(ty << 3) + 4];
    float xv[8] = {x0.x, x0.y, x0.z, x0.w, x1.x, x1.y, x1.z, x1.w};
    float wv[8] = {w0.x, w0.y, w0.z, w0.w, w1.x, w1.y, w1.z, w1.w};
#pragma unroll
    for (int r = 0; r < 8; ++r)
#pragma unroll
      for (int c = 0; c < 8; ++c) acc[r][c] = fmaf(xv[r], wv[c], acc[r][c]);
  }
#pragma unroll
  for (int r = 0; r < 8; ++r) {
    int row = row0 + (ty << 3) + r;
    if (row < n) {
      float4* yp = (float4*)(p.Y + (size_t)row * 128 + (tx << 3));
      yp[0] = make_float4(acc[r][0], acc[r][1], acc[r][2], acc[r][3]);
      yp[1] = make_float4(acc[r][4], acc[r][5], acc[r][6], acc[r][7]);
    }
  }
  // ---- fused el/er epilogue ----
  float al_v[8], ar_v[8];
  {
    const float4* al4 = (const float4*)p.al;
    const float4* ar4 = (const float4*)p.ar;
    float4 a0 = al4[tx * 2], a1 = al4[tx * 2 + 1];
    float4 r0 = ar4[tx * 2], r1 = ar4[tx * 2 + 1];
    al_v[0] = a0.x; al_v[1] = a0.y; al_v[2] = a0.z; al_v[3] = a0.w;
    al_v[4] = a1.x; al_v[5] = a1.y; al_v[6] = a1.z; al_v[7] = a1.w;
    ar_v[0] = r0.x; ar_v[1] = r0.y; ar_v[2] = r0.z; ar_v[3] = r0.w;
    ar_v[4] = r1.x; ar_v[5] = r1.y; ar_v[6] = r1.z; ar_v[7] = r1.w;
  }
  __syncthreads();  // reuse xs as reduction scratch
  float* redl = &xs[0][0];        // [128][17]
  float* redr = redl + 128 * 17;  // [128][17]
#pragma unroll
  for (int r = 0; r < 8; ++r) {
    float pl = 0.f, pr = 0.f;
#pragma unroll
    for (int c = 0; c < 8; ++c) {
      pl = fmaf(acc[r][c], al_v[c], pl);
      pr = fmaf(acc[r][c], ar_v[c], pr);
    }
    redl[((ty << 3) + r) * 17 + tx] = pl;
    redr[((ty << 3) + r) * 17 + tx] = pr;
  }
  __syncthreads();
  if (t < 128) {
    int row = row0 + t;
    if (row < n) {
      float s[4], q[4];
#pragma unroll
      for (int h = 0; h < 4; ++h) {
        int b = t * 17 + h * 4;
        s[h] = redl[b] + redl[b + 1] + redl[b + 2] + redl[b + 3];
        q[h] = redr[b] + redr[b + 1] + redr[b + 2] + redr[b + 3];
      }
      *(float4*)(p.el + (size_t)row * 4) = make_float4(s[0], s[1], s[2], s[3]);
      *(float4*)(p.er + (size_t)row * 4) = make_float4(q[0], q[1], q[2], q[3]);
    }
  }
}

// One node per block. Threads 0-127: channel c0, 128-255: channel c1; j = h*32+f.
// Per 64-edge chunk: stage src indices + unnormalized coefs exp(e)*w in LDS
// (each thread computes 2 coefs), accumulate denominator l = sum exp(e) in
// registers, then 1-FMA-per-edge feature accumulation. out = acc/max(l,1e-9)+b.
template <int LAYER>
__global__ __launch_bounds__(256) void gather_kernel(ChP c0, ChP c1,
                                                     const int* __restrict__ offs,
                                                     const int* __restrict__ csr_src, int n) {
  int t = threadIdx.x;
  int ch = t >> 7;
  int j = t & 127;
  int h = j >> 5;
  ChP P = ch ? c1 : c0;
  int node = blockIdx.x;
  int se = (t >> 1) & 63;  // staging edge slot
  int hp = t & 1;          // staging head pair (heads 2hp, 2hp+1)
  float2 er2 = *(const float2*)(P.er + (size_t)node * 4 + hp * 2);

  __shared__ int s_src[64];
  __shared__ float s_coef[2][64][4];
  __shared__ float s_lred[2][4][64];
  __shared__ float s_out[256];

  int start = offs[node], end = offs[node + 1];
  float acc = 0.f, lp0 = 0.f, lp1 = 0.f;
  for (int base = start; base < end; base += 64) {
    int cnt = min(64, end - base);
    __syncthreads();  // protect s_src/s_coef from previous chunk's readers
    if (se < cnt) {
      int s = csr_src[base + se];
      if (t < 128 && hp == 0) s_src[se] = s;  // ch==0 && hp==0 writers
      float w = P.w[base + se];
      float2 el2 = *(const float2*)(P.el + (size_t)s * 4 + hp * 2);
      float e0 = el2.x + er2.x; e0 = (e0 > 0.f) ? e0 : 0.2f * e0;
      float e1 = el2.y + er2.y; e1 = (e1 > 0.f) ? e1 : 0.2f * e1;
      float x0 = __expf(e0), x1 = __expf(e1);
      lp0 += x0; lp1 += x1;
      s_coef[ch][se][hp * 2 + 0] = x0 * w;
      s_coef[ch][se][hp * 2 + 1] = x1 * w;
    }
    __syncthreads();
    int k = 0;
    for (; k + 8 <= cnt; k += 8) {
      int s0 = s_src[k + 0], s1 = s_src[k + 1], s2 = s_src[k + 2], s3 = s_src[k + 3];
      int s4 = s_src[k + 4], s5 = s_src[k + 5], s6 = s_src[k + 6], s7 = s_src[k + 7];
      float f0 = P.ft[s0 * 128 + j], f1 = P.ft[s1 * 128 + j];
      float f2 = P.ft[s2 * 128 + j], f3 = P.ft[s3 * 128 + j];
      float f4 = P.ft[s4 * 128 + j], f5 = P.ft[s5 * 128 + j];
      float f6 = P.ft[s6 * 128 + j], f7 = P.ft[s7 * 128 + j];
      float c0v = s_coef[ch][k + 0][h], c1v = s_coef[ch][k + 1][h];
      float c2v = s_coef[ch][k + 2][h], c3v = s_coef[ch][k + 3][h];
      float c4v = s_coef[ch][k + 4][h], c5v = s_coef[ch][k + 5][h];
      float c6v = s_coef[ch][k + 6][h], c7v = s_coef[ch][k + 7][h];
      acc = fmaf(c0v, f0, acc); acc = fmaf(c1v, f1, acc);
      acc = fmaf(c2v, f2, acc); acc = fmaf(c3v, f3, acc);
      acc = fmaf(c4v, f4, acc); acc = fmaf(c5v, f5, acc);
      acc = fmaf(c6v, f6, acc); acc = fmaf(c7v, f7, acc);
    }
    for (; k < cnt; ++k) {
      acc = fmaf(s_coef[ch][k][h], P.ft[s_src[k] * 128 + j], acc);
    }
  }
  // denominator reduction: l[ch][h] = sum over 64 staging slots
  __syncthreads();
  s_lred[ch][hp * 2 + 0][se] = lp0;
  s_lred[ch][hp * 2 + 1][se] = lp1;
  __syncthreads();
  float l = 0.f;
  const float4* lr4 = (const float4*)&s_lred[ch][h][0];
#pragma unroll
  for (int i = 0; i < 16; ++i) {
    float4 q = lr4[i];
    l += q.x + q.y + q.z + q.w;
  }
  float v = acc * (1.f / fmaxf(l, 1e-9f)) + P.bias[j];
  if (LAYER == 0) {
    P.out[(size_t)node * 128 + j] = fmaxf(v, 0.f);
  } else {
    s_out[t] = v;
    __syncthreads();
    if (j < 32) {
      int b = (ch << 7) + j;
      float s4 = s_out[b] + s_out[b + 32] + s_out[b + 64] + s_out[b + 96];
      P.out[(size_t)node * 32 + j] = 0.25f * s4;
    }
  }
}

extern "C" void kernel_launch(void* const* d_in, const int* in_sizes, int n_in,
                              void* d_out, int out_size, void* d_ws, size_t ws_size,
                              hipStream_t stream) {
  const float* x_am = (const float*)d_in[0];
  const float* x_ph = (const float*)d_in[1];
  const float* exist = (const float*)d_in[2];
  const float* am_exist = (const float*)d_in[3];
  const int* src = (const int*)d_in[4];
  const int* dst = (const int*)d_in[5];
  const float* W0a = (const float*)d_in[6];
  const float* al0a = (const float*)d_in[7];
  const float* ar0a = (const float*)d_in[8];
  const float* b0a = (const float*)d_in[9];
  const float* W0p = (const float*)d_in[10];
  const float* al0p = (const float*)d_in[11];
  const float* ar0p = (const float*)d_in[12];
  const float* b0p = (const float*)d_in[13];
  const float* W1a = (const float*)d_in[14];
  const float* al1a = (const float*)d_in[15];
  const float* ar1a = (const float*)d_in[16];
  const float* b1a = (const float*)d_in[17];
  const float* W1p = (const float*)d_in[18];
  const float* al1p = (const float*)d_in[19];
  const float* ar1p = (const float*)d_in[20];
  const float* b1p = (const float*)d_in[21];

  int n = in_sizes[0] / 128;  // 50000
  int E = in_sizes[2];        // 800000
  int N_pad = (n + 255) & ~255;
  int nb = (n + 255) / 256;
  int NB_pad = (nb + 63) & ~63;

  size_t szN = (size_t)N_pad * 4;
  size_t szOffs = (size_t)(N_pad + 8) * 4;
  size_t szE = (size_t)E * 4;
  size_t szFt = (size_t)n * 128 * 4;
  size_t szEl = (size_t)N_pad * 4 * 4;

  auto rnd = [](size_t b) { return (b + 255) & ~(size_t)255; };
  size_t fixed = 3 * rnd(szN) + rnd((size_t)NB_pad * 4) + rnd(szOffs) + 3 * rnd(szE) +
                 4 * rnd(szEl);
  bool dual = ws_size >= fixed + 4 * rnd(szFt);

  char* p = (char*)d_ws;
  auto take = [&](size_t b) { char* q = p; p += (b + 255) & ~(size_t)255; return q; };
  int* counts = (int*)take(szN);
  int* cursor = (int*)take(szN);
  int* incl = (int*)take(szN);
  int* bsum = (int*)take((size_t)NB_pad * 4);
  int* offs = (int*)take(szOffs);
  int* csr_src = (int*)take(szE);
  float* w_am = (float*)take(szE);
  float* w_ph = (float*)take(szE);
  float* el_am = (float*)take(szEl);
  float* el_ph = (float*)take(szEl);
  float* er_am = (float*)take(szEl);
  float* er_ph = (float*)take(szEl);
  float* ft_am = (float*)take(szFt);
  float* ft_ph = dual ? (float*)take(szFt) : ft_am;
  float* hb_am = (float*)take(szFt);
  float* hb_ph = dual ? (float*)take(szFt) : hb_am;

  float* out_am = (float*)d_out;
  float* out_ph = out_am + (size_t)n * 32;

  // ---- CSR build ----
  hipMemsetAsync(counts, 0, szN, stream);
  hipMemsetAsync(cursor, 0, szN, stream);
  hist_kernel<<<(E + 255) / 256, 256, 0, stream>>>(dst, counts, E);
  scan1_kernel<<<nb, 256, 0, stream>>>(counts, incl, bsum, n);
  scan2_kernel<<<1, 256, 0, stream>>>(bsum, nb);
  scan3_kernel<<<nb, 256, 0, stream>>>(counts, incl, bsum, offs, n, E);
  fill_kernel<<<(E + 255) / 256, 256, 0, stream>>>(src, dst, exist, am_exist, offs,
                                                   cursor, csr_src, w_am, w_ph, E);

  int gg = (n + 127) / 128;
  GemmP g0a{x_am, W0a, al0a, ar0a, ft_am, el_am, er_am};
  GemmP g0p{x_ph, W0p, al0p, ar0p, ft_ph, el_ph, er_ph};
  GemmP g1a{hb_am, W1a, al1a, ar1a, ft_am, el_am, er_am};
  GemmP g1p{hb_ph, W1p, al1p, ar1p, ft_ph, el_ph, er_ph};
  ChP c0a{ft_am, el_am, er_am, w_am, b0a, hb_am};
  ChP c0p{ft_ph, el_ph, er_ph, w_ph, b0p, hb_ph};
  ChP c1a{ft_am, el_am, er_am, w_am, b1a, out_am};
  ChP c1p{ft_ph, el_ph, er_ph, w_ph, b1p, out_ph};

  if (dual) {
    gemm_kernel<<<dim3(gg, 2), 256, 0, stream>>>(g0a, g0p, n);
    gather_kernel<0><<<n, 256, 0, stream>>>(c0a, c0p, offs, csr_src, n);
    gemm_kernel<<<dim3(gg, 2), 256, 0, stream>>>(g1a, g1p, n);
    gather_kernel<1><<<n, 256, 0, stream>>>(c1a, c1p, offs, csr_src, n);
  } else {
    // sequential fallback: both grid.y slices run the same channel (benign
    // duplicate writes of identical values); buffers aliased above.
    gemm_kernel<<<dim3(gg, 2), 256, 0, stream>>>(g0a, g0a, n);
    gather_kernel<0><<<n, 256, 0, stream>>>(c0a, c0a, offs, csr_src, n);
    gemm_kernel<<<dim3(gg, 2), 256, 0, stream>>>(g1a, g1a, n);
    gather_kernel<1><<<n, 256, 0, stream>>>(c1a, c1a, offs, csr_src, n);
    gemm_kernel<<<dim3(gg, 2), 256, 0, stream>>>(g0p, g0p, n);
    gather_kernel<0><<<n, 256, 0, stream>>>(c0p, c0p, offs, csr_src, n);
    gemm_kernel<<<dim3(gg, 2), 256, 0, stream>>>(g1p, g1p, n);
    gather_kernel<1><<<n, 256, 0, stream>>>(c1p, c1p, offs, csr_src, n);
  }
}